// Round 3
// baseline (518.523 us; speedup 1.0000x reference)
//
#include <hip/hip_runtime.h>
#include <hip/hip_bf16.h>
#include <cstdint>
#include <cstddef>

#define NB 8
#define NS 1024
#define NH 1024
#define ND 64

typedef __attribute__((ext_vector_type(8))) short bf8_t;
typedef __attribute__((ext_vector_type(4))) float f32x4;
typedef __attribute__((ext_vector_type(4))) short short4v;

__device__ __forceinline__ short f2bfs(float x) {
    union { __hip_bfloat16 h; short s; } u;
    u.h = __float2bfloat16(x);
    return u.s;
}
__device__ __forceinline__ float bf2f(short h) {
    return __uint_as_float(((unsigned int)(unsigned short)h) << 16);
}
__device__ __forceinline__ bf8_t pack_bf8(float4 a, float4 b) {
    bf8_t r;
    r[0] = f2bfs(a.x); r[1] = f2bfs(a.y); r[2] = f2bfs(a.z); r[3] = f2bfs(a.w);
    r[4] = f2bfs(b.x); r[5] = f2bfs(b.y); r[6] = f2bfs(b.z); r[7] = f2bfs(b.w);
    return r;
}

// ws layout (shorts): qp[8][1024][64] @0 (scaled 1/8), kp @524288, vpT[8][64][1024] @1048576
#define QP_OFF 0
#define KP_OFF 524288
#define VPT_OFF 1048576

// ---------------------------------------------------------------------------
// Projection via MFMA: dst = A(fp32)@W(fp32) + bias, stored bf16.
// grid (128, 3), block 256 (4 waves x 16 rows = 64 rows/WG).
// ---------------------------------------------------------------------------
__global__ __launch_bounds__(256, 2) void proj_kernel(
    const float* __restrict__ qin, const float* __restrict__ kin, const float* __restrict__ vin,
    const float* __restrict__ Wq, const float* __restrict__ bq,
    const float* __restrict__ Wk, const float* __restrict__ bk,
    const float* __restrict__ Wv, const float* __restrict__ bv,
    short* __restrict__ ws_s)
{
    __shared__ short Wt[64][136];   // W transposed bf16, row stride 272B (16B-mult, 2-way banks)

    const int p = blockIdx.y;
    const float* A    = (p == 0) ? qin : (p == 1) ? kin : vin;
    const float* W    = (p == 0) ? Wq  : (p == 1) ? Wk  : Wv;
    const float* bias = (p == 0) ? bq  : (p == 1) ? bk  : bv;

    const int t  = threadIdx.x;
    const int wv = t >> 6, l = t & 63, lr = l & 15, lg = l >> 4;
    const int r0 = blockIdx.x * 64;
    const int rw = r0 + wv * 16;          // this wave's 16 rows

    const int sk  = t & 127;              // staging: k-row within chunk
    const int snh = (t >> 7) * 32;        // staging: n-half

    f32x4 acc[4];
    #pragma unroll
    for (int n = 0; n < 4; ++n) acc[n] = (f32x4){0.f, 0.f, 0.f, 0.f};

    for (int ch = 0; ch < 8; ++ch) {      // k-chunks of 128
        __syncthreads();
        {   // stage Wt[n][kk] = bf16(W[ch*128+kk][n])
            const float* wp = &W[(size_t)(ch * 128 + sk) * ND + snh];
            #pragma unroll
            for (int j = 0; j < 8; ++j) {
                float4 w4 = *(const float4*)&wp[4 * j];
                Wt[snh + 4 * j + 0][sk] = f2bfs(w4.x);
                Wt[snh + 4 * j + 1][sk] = f2bfs(w4.y);
                Wt[snh + 4 * j + 2][sk] = f2bfs(w4.z);
                Wt[snh + 4 * j + 3][sk] = f2bfs(w4.w);
            }
        }
        __syncthreads();
        #pragma unroll
        for (int s = 0; s < 4; ++s) {     // 4 k-steps of 32
            const float* ap = &A[(size_t)(rw + lr) * NH + ch * 128 + s * 32 + lg * 8];
            float4 a0 = *(const float4*)ap;
            float4 a1 = *(const float4*)(ap + 4);
            bf8_t af = pack_bf8(a0, a1);
            #pragma unroll
            for (int n = 0; n < 4; ++n) {
                bf8_t bf = *(const bf8_t*)&Wt[n * 16 + lr][s * 32 + lg * 8];
                acc[n] = __builtin_amdgcn_mfma_f32_16x16x32_bf16(af, bf, acc[n], 0, 0, 0);
            }
        }
    }

    // epilogue: D row = lg*4+reg, col = n*16+lr
    if (p < 2) {
        short* dst = ws_s + ((p == 0) ? QP_OFF : KP_OFF);
        const float sc = (p == 0) ? 0.125f : 1.0f;
        #pragma unroll
        for (int n = 0; n < 4; ++n) {
            const float bs = bias[n * 16 + lr];
            #pragma unroll
            for (int r = 0; r < 4; ++r) {
                float v = (acc[n][r] + bs) * sc;
                dst[(size_t)(rw + lg * 4 + r) * ND + n * 16 + lr] = f2bfs(v);
            }
        }
    } else {
        short* vpT = ws_s + VPT_OFF;
        const int b = rw >> 10;
        const int sbase = (rw & 1023) + lg * 4;
        #pragma unroll
        for (int n = 0; n < 4; ++n) {
            const float bs = bias[n * 16 + lr];
            short4v pk;
            #pragma unroll
            for (int r = 0; r < 4; ++r) pk[r] = f2bfs(acc[n][r] + bs);
            *(short4v*)&vpT[((size_t)b * 64 + n * 16 + lr) * NS + sbase] = pk;
        }
    }
}

// ---------------------------------------------------------------------------
// Fused attention, MFMA: one WG per q row, 4 waves splitting k in quarters.
// ---------------------------------------------------------------------------
__global__ __launch_bounds__(256, 3) void attn_kernel(
    const short* __restrict__ ws_s,
    const float* __restrict__ kbias, const float* __restrict__ vbias,
    const int* __restrict__ mask,
    float* __restrict__ out)
{
    __shared__ short w_lds[16][1032];     // rows 0-7 = scores/weights; stride 2064B (16B-mult, 2-way)
    __shared__ float red_a[4][8][64];     // O2 (VALU) partials
    __shared__ float red_b[4][8][64];     // O1 (MFMA) partials

    const short* qp  = ws_s + QP_OFF;
    const short* kp  = ws_s + KP_OFF;
    const short* vpT = ws_s + VPT_OFF;

    const int q = blockIdx.x, t = threadIdx.x;
    const int wv = t >> 6, l = t & 63, lr = l & 15, lg = l >> 4;
    const bf8_t zero8 = {0, 0, 0, 0, 0, 0, 0, 0};

    // A-frag: rows = batch (rows 8-15 read into kp region -> garbage, always masked/unused)
    const bf8_t aq0 = *(const bf8_t*)&qp[((size_t)lr * NS + q) * ND + lg * 8];
    const bf8_t aq1 = *(const bf8_t*)&qp[((size_t)lr * NS + q) * ND + 32 + lg * 8];

    const float* kbq = kbias + (size_t)q * (NS * ND);
    const float* vbq = vbias + (size_t)q * (NS * ND);

    // ---- scores: S[b][k] = q_b . kbias[q,k]  +  q_b . kp[b,k]  (block-diag trick) ----
    for (int tl = 0; tl < 16; ++tl) {
        const int k0 = wv * 256 + tl * 16;
        f32x4 s0 = {0.f, 0.f, 0.f, 0.f}, s1 = {0.f, 0.f, 0.f, 0.f};

        const float* kb = &kbq[(size_t)(k0 + lr) * ND + lg * 8];
        bf8_t bb0 = pack_bf8(*(const float4*)&kb[0],  *(const float4*)&kb[4]);
        bf8_t bb1 = pack_bf8(*(const float4*)&kb[32], *(const float4*)&kb[36]);
        s0 = __builtin_amdgcn_mfma_f32_16x16x32_bf16(aq0, bb0, s0, 0, 0, 0);
        s1 = __builtin_amdgcn_mfma_f32_16x16x32_bf16(aq1, bb1, s1, 0, 0, 0);

        #pragma unroll
        for (int bp = 0; bp < 8; ++bp) {
            const short* kpp = &kp[((size_t)bp * NS + k0 + lr) * ND];
            bf8_t bc0 = *(const bf8_t*)&kpp[lg * 8];
            bf8_t bc1 = *(const bf8_t*)&kpp[32 + lg * 8];
            bf8_t a0 = (lr == bp) ? aq0 : zero8;
            bf8_t a1 = (lr == bp) ? aq1 : zero8;
            s0 = __builtin_amdgcn_mfma_f32_16x16x32_bf16(a0, bc0, s0, 0, 0, 0);
            s1 = __builtin_amdgcn_mfma_f32_16x16x32_bf16(a1, bc1, s1, 0, 0, 0);
        }
        if (lg < 2) {
            #pragma unroll
            for (int r = 0; r < 4; ++r) {
                const int b = lg * 4 + r, k = k0 + lr;
                float sv = s0[r] + s1[r];
                if (mask[b * NS + k] == 0) sv = -1e9f;
                w_lds[b][k] = f2bfs(sv);
            }
        }
    }
    __syncthreads();

    // ---- softmax per batch row (8 rows x 32 lanes), normalize in place ----
    {
        const int row = t >> 5, idx = t & 31;
        const float LOG2E = 1.4426950408889634f;
        float sv[32];
        float m = -3.0e38f;
        #pragma unroll
        for (int i = 0; i < 16; ++i) {
            unsigned int pr = *(const unsigned int*)&w_lds[row][2 * idx + 64 * i];
            sv[2 * i]     = __uint_as_float(pr << 16);
            sv[2 * i + 1] = __uint_as_float(pr & 0xffff0000u);
            m = fmaxf(m, fmaxf(sv[2 * i], sv[2 * i + 1]));
        }
        #pragma unroll
        for (int off = 1; off < 32; off <<= 1) m = fmaxf(m, __shfl_xor(m, off, 32));
        float lsum = 0.f;
        #pragma unroll
        for (int i = 0; i < 32; ++i) { sv[i] = exp2f((sv[i] - m) * LOG2E); lsum += sv[i]; }
        #pragma unroll
        for (int off = 1; off < 32; off <<= 1) lsum += __shfl_xor(lsum, off, 32);
        const float il = 1.0f / fmaxf(lsum, 1e-30f);
        #pragma unroll
        for (int i = 0; i < 16; ++i) {
            unsigned int lo = (unsigned int)(unsigned short)f2bfs(sv[2 * i] * il);
            unsigned int hi = (unsigned int)(unsigned short)f2bfs(sv[2 * i + 1] * il);
            *(unsigned int*)&w_lds[row][2 * idx + 64 * i] = (hi << 16) | lo;
        }
    }
    __syncthreads();

    // ---- O1: sum_k w[b,k] * vp[b,k,d] via block-diag MFMA over (b',k) ----
    f32x4 o[4];
    #pragma unroll
    for (int n = 0; n < 4; ++n) o[n] = (f32x4){0.f, 0.f, 0.f, 0.f};

    for (int kw = 0; kw < 8; ++kw) {
        const int k0 = wv * 256 + kw * 32;
        const bf8_t aw = *(const bf8_t*)&w_lds[lr][k0 + lg * 8];
        #pragma unroll
        for (int bp = 0; bp < 8; ++bp) {
            const bf8_t am = (lr == bp) ? aw : zero8;
            #pragma unroll
            for (int n = 0; n < 4; ++n) {
                const bf8_t bf = *(const bf8_t*)&vpT[((size_t)bp * 64 + n * 16 + lr) * NS + k0 + lg * 8];
                o[n] = __builtin_amdgcn_mfma_f32_16x16x32_bf16(am, bf, o[n], 0, 0, 0);
            }
        }
    }

    // ---- O2: sum_k w[b,k] * vbias[q,k,d] via coalesced fp32 VALU ----
    float4 av[8];
    #pragma unroll
    for (int b = 0; b < 8; ++b) av[b] = make_float4(0.f, 0.f, 0.f, 0.f);

    for (int kw = 0; kw < 8; ++kw) {
        #pragma unroll
        for (int i = 0; i < 8; ++i) {
            const int k = wv * 256 + kw * 32 + lg + 4 * i;
            const float4 vb = *(const float4*)&vbq[(size_t)k * ND + 4 * lr];
            #pragma unroll
            for (int b = 0; b < 8; ++b) {
                const float w = bf2f(w_lds[b][k]);
                av[b].x += w * vb.x; av[b].y += w * vb.y;
                av[b].z += w * vb.z; av[b].w += w * vb.w;
            }
        }
    }
    #pragma unroll
    for (int b = 0; b < 8; ++b) {
        #pragma unroll
        for (int off = 16; off <= 32; off <<= 1) {
            av[b].x += __shfl_xor(av[b].x, off, 64);
            av[b].y += __shfl_xor(av[b].y, off, 64);
            av[b].z += __shfl_xor(av[b].z, off, 64);
            av[b].w += __shfl_xor(av[b].w, off, 64);
        }
    }
    if (l < 16) {
        #pragma unroll
        for (int b = 0; b < 8; ++b) *(float4*)&red_a[wv][b][4 * lr] = av[b];
    }
    if (lg < 2) {
        #pragma unroll
        for (int n = 0; n < 4; ++n)
            #pragma unroll
            for (int r = 0; r < 4; ++r)
                red_b[wv][lg * 4 + r][n * 16 + lr] = o[n][r];
    }
    __syncthreads();

    if (t < 128) {
        const int b = t >> 4, d = (t & 15) * 4;
        float4 s = make_float4(0.f, 0.f, 0.f, 0.f);
        #pragma unroll
        for (int w4 = 0; w4 < 4; ++w4) {
            float4 ra = *(const float4*)&red_a[w4][b][d];
            float4 rb = *(const float4*)&red_b[w4][b][d];
            s.x += ra.x + rb.x; s.y += ra.y + rb.y;
            s.z += ra.z + rb.z; s.w += ra.w + rb.w;
        }
        *(float4*)&out[((size_t)b * NS + q) * ND + d] = s;
    }
}

extern "C" void kernel_launch(void* const* d_in, const int* in_sizes, int n_in,
                              void* d_out, int out_size, void* d_ws, size_t ws_size,
                              hipStream_t stream) {
    (void)in_sizes; (void)n_in; (void)out_size; (void)ws_size;
    const float* query = (const float*)d_in[0];
    const float* key   = (const float*)d_in[1];
    const float* value = (const float*)d_in[2];
    const float* Wq    = (const float*)d_in[3];
    const float* bq    = (const float*)d_in[4];
    const float* Wk    = (const float*)d_in[5];
    const float* bk    = (const float*)d_in[6];
    const float* Wv    = (const float*)d_in[7];
    const float* bv    = (const float*)d_in[8];
    const float* kbias = (const float*)d_in[9];
    const float* vbias = (const float*)d_in[10];
    const int*   mask  = (const int*)d_in[11];
    short* ws_s = (short*)d_ws;
    float* outp = (float*)d_out;

    dim3 gp(128, 3), bp(256);
    proj_kernel<<<gp, bp, 0, stream>>>(query, key, value, Wq, bq, Wk, bk, Wv, bv, ws_s);
    attn_kernel<<<NS, 256, 0, stream>>>(ws_s, kbias, vbias, mask, outp);
}

// Round 4
// 231.356 us; speedup vs baseline: 2.2412x; 2.2412x over previous
//
#include <hip/hip_runtime.h>
#include <hip/hip_bf16.h>
#include <cstdint>
#include <cstddef>

#define NB 8
#define NS 1024
#define NH 1024
#define ND 64

typedef __attribute__((ext_vector_type(8))) short bf8_t;
typedef __attribute__((ext_vector_type(4))) float f32x4;
typedef __attribute__((ext_vector_type(4))) short short4v;

__device__ __forceinline__ short f2bfs(float x) {
    union { __hip_bfloat16 h; short s; } u;
    u.h = __float2bfloat16(x);
    return u.s;
}
__device__ __forceinline__ float bf2f(unsigned short h) {
    return __uint_as_float(((unsigned int)h) << 16);
}
__device__ __forceinline__ bf8_t pack_bf8(float4 a, float4 b) {
    bf8_t r;
    r[0] = f2bfs(a.x); r[1] = f2bfs(a.y); r[2] = f2bfs(a.z); r[3] = f2bfs(a.w);
    r[4] = f2bfs(b.x); r[5] = f2bfs(b.y); r[6] = f2bfs(b.z); r[7] = f2bfs(b.w);
    return r;
}

// ws layout (shorts):
//   qp [8][1024][64] bf16 (scaled 1/8)   @ QP_OFF
//   kp [8][1024][64] bf16                @ KP_OFF
//   vpT[8][64][1024] bf16                @ VPT_OFF
//   S1 [8][1024][1024] bf16 (scores -> softmax weights, in place) @ S1_OFF
//   S2 [1024][8][1024] bf16 (bias-term scores)                    @ S2_OFF
// total = 18,350,080 shorts = 36.7 MB
#define QP_OFF  0
#define KP_OFF  524288
#define VPT_OFF 1048576
#define S1_OFF  1572864
#define S2_OFF  9961472

// ---------------------------------------------------------------------------
// Projection via MFMA: qp (x1/8), kp row-major bf16; vpT [b][d][s] bf16.
// grid (128, 3), block 256 (4 waves x 16 rows = 64 rows/WG).
// ---------------------------------------------------------------------------
__global__ __launch_bounds__(256, 2) void proj_kernel(
    const float* __restrict__ qin, const float* __restrict__ kin, const float* __restrict__ vin,
    const float* __restrict__ Wq, const float* __restrict__ bq,
    const float* __restrict__ Wk, const float* __restrict__ bk,
    const float* __restrict__ Wv, const float* __restrict__ bv,
    short* __restrict__ ws_s)
{
    __shared__ short Wt[64][136];

    const int p = blockIdx.y;
    const float* A    = (p == 0) ? qin : (p == 1) ? kin : vin;
    const float* W    = (p == 0) ? Wq  : (p == 1) ? Wk  : Wv;
    const float* bias = (p == 0) ? bq  : (p == 1) ? bk  : bv;

    const int t  = threadIdx.x;
    const int wv = t >> 6, l = t & 63, lr = l & 15, lg = l >> 4;
    const int rw = blockIdx.x * 64 + wv * 16;

    const int sk  = t & 127;
    const int snh = (t >> 7) * 32;

    f32x4 acc[4];
    #pragma unroll
    for (int n = 0; n < 4; ++n) acc[n] = (f32x4){0.f, 0.f, 0.f, 0.f};

    for (int ch = 0; ch < 8; ++ch) {
        __syncthreads();
        {
            const float* wp = &W[(size_t)(ch * 128 + sk) * ND + snh];
            #pragma unroll
            for (int j = 0; j < 8; ++j) {
                float4 w4 = *(const float4*)&wp[4 * j];
                Wt[snh + 4 * j + 0][sk] = f2bfs(w4.x);
                Wt[snh + 4 * j + 1][sk] = f2bfs(w4.y);
                Wt[snh + 4 * j + 2][sk] = f2bfs(w4.z);
                Wt[snh + 4 * j + 3][sk] = f2bfs(w4.w);
            }
        }
        __syncthreads();
        #pragma unroll
        for (int s = 0; s < 4; ++s) {
            const float* ap = &A[(size_t)(rw + lr) * NH + ch * 128 + s * 32 + lg * 8];
            bf8_t af = pack_bf8(*(const float4*)ap, *(const float4*)(ap + 4));
            #pragma unroll
            for (int n = 0; n < 4; ++n) {
                bf8_t bf = *(const bf8_t*)&Wt[n * 16 + lr][s * 32 + lg * 8];
                acc[n] = __builtin_amdgcn_mfma_f32_16x16x32_bf16(af, bf, acc[n], 0, 0, 0);
            }
        }
    }

    if (p < 2) {
        short* dst = ws_s + ((p == 0) ? QP_OFF : KP_OFF);
        const float sc = (p == 0) ? 0.125f : 1.0f;
        #pragma unroll
        for (int n = 0; n < 4; ++n) {
            const float bs = bias[n * 16 + lr];
            #pragma unroll
            for (int r = 0; r < 4; ++r)
                dst[(size_t)(rw + lg * 4 + r) * ND + n * 16 + lr] = f2bfs((acc[n][r] + bs) * sc);
        }
    } else {
        short* vpT = ws_s + VPT_OFF;
        const int b = rw >> 10;
        const int sbase = (rw & 1023) + lg * 4;
        #pragma unroll
        for (int n = 0; n < 4; ++n) {
            const float bs = bias[n * 16 + lr];
            short4v pk;
            #pragma unroll
            for (int r = 0; r < 4; ++r) pk[r] = f2bfs(acc[n][r] + bs);
            *(short4v*)&vpT[((size_t)b * 64 + n * 16 + lr) * NS + sbase] = pk;
        }
    }
}

// ---------------------------------------------------------------------------
// Scores: S1[b][q][k] = qp_b . kp_b   (content, full-M MFMA)
//         S2[q][b][k] = qp_:  . kbias (bias term, M=8/16, coalesced kbias)
// grid (8 kblk, 64 qblk), block 256; wave owns 32 k's.
// ---------------------------------------------------------------------------
__global__ __launch_bounds__(256, 2) void scores_kernel(
    const short* __restrict__ ws_s,
    const float* __restrict__ kbias,
    short* __restrict__ s1, short* __restrict__ s2)
{
    const short* qp = ws_s + QP_OFF;
    const short* kp = ws_s + KP_OFF;
    const int t = threadIdx.x;
    const int wv = t >> 6, l = t & 63, lr = l & 15, lg = l >> 4;
    const int q0 = blockIdx.y * 16;
    const int kbase = blockIdx.x * 128 + wv * 32;

    for (int st = 0; st < 2; ++st) {
        const int k0 = kbase + st * 16;

        // content term
        #pragma unroll
        for (int b = 0; b < 8; ++b) {
            const short* ap = &qp[((size_t)b * NS + q0 + lr) * ND + lg * 8];
            const short* bp = &kp[((size_t)b * NS + k0 + lr) * ND + lg * 8];
            bf8_t a0 = *(const bf8_t*)ap;
            bf8_t a1 = *(const bf8_t*)(ap + 32);
            bf8_t b0 = *(const bf8_t*)bp;
            bf8_t b1 = *(const bf8_t*)(bp + 32);
            f32x4 acc = {0.f, 0.f, 0.f, 0.f};
            acc = __builtin_amdgcn_mfma_f32_16x16x32_bf16(a0, b0, acc, 0, 0, 0);
            acc = __builtin_amdgcn_mfma_f32_16x16x32_bf16(a1, b1, acc, 0, 0, 0);
            #pragma unroll
            for (int r = 0; r < 4; ++r)
                s1[((size_t)b * NS + q0 + lg * 4 + r) * NS + k0 + lr] = f2bfs(acc[r]);
        }

        // bias term
        #pragma unroll 4
        for (int qq = 0; qq < 16; ++qq) {
            const short* ap = &qp[((size_t)(lr & 7) * NS + q0 + qq) * ND + lg * 8];
            bf8_t a0 = *(const bf8_t*)ap;
            bf8_t a1 = *(const bf8_t*)(ap + 32);
            const float* kb = &kbias[((size_t)(q0 + qq) * NS + k0 + lr) * ND + lg * 8];
            bf8_t b0 = pack_bf8(*(const float4*)kb, *(const float4*)(kb + 4));
            bf8_t b1 = pack_bf8(*(const float4*)(kb + 32), *(const float4*)(kb + 36));
            f32x4 acc = {0.f, 0.f, 0.f, 0.f};
            acc = __builtin_amdgcn_mfma_f32_16x16x32_bf16(a0, b0, acc, 0, 0, 0);
            acc = __builtin_amdgcn_mfma_f32_16x16x32_bf16(a1, b1, acc, 0, 0, 0);
            if (lg < 2) {
                #pragma unroll
                for (int r = 0; r < 4; ++r)
                    s2[((size_t)(q0 + qq) * NB + lg * 4 + r) * NS + k0 + lr] = f2bfs(acc[r]);
            }
        }
    }
}

// ---------------------------------------------------------------------------
// Softmax: per row (b,q): w = softmax(mask(S1+S2)), written in place to S1.
// grid 2048, block 256; one wave per row.
// ---------------------------------------------------------------------------
__global__ __launch_bounds__(256, 4) void softmax_kernel(
    short* __restrict__ s1, const short* __restrict__ s2,
    const int* __restrict__ mask)
{
    const int t = threadIdx.x, wv = t >> 6, l = t & 63;
    const int row = blockIdx.x * 4 + wv;      // b*NS + q
    const int b = row >> 10, q = row & 1023;
    short* r1 = s1 + (size_t)row * NS;
    const short* r2 = s2 + ((size_t)q * NB + b) * NS;
    const int* mb = mask + b * NS;
    const float LOG2E = 1.4426950408889634f;
    const int k0 = l * 16;

    unsigned short sa[16], sb[16];
    *(uint4*)&sa[0] = *(const uint4*)&r1[k0];
    *(uint4*)&sa[8] = *(const uint4*)&r1[k0 + 8];
    *(uint4*)&sb[0] = *(const uint4*)&r2[k0];
    *(uint4*)&sb[8] = *(const uint4*)&r2[k0 + 8];
    int mv[16];
    #pragma unroll
    for (int j = 0; j < 4; ++j) *(int4*)&mv[4 * j] = *(const int4*)&mb[k0 + 4 * j];

    float x[16];
    float m = -3.0e38f;
    #pragma unroll
    for (int j = 0; j < 16; ++j) {
        float v = bf2f(sa[j]) + bf2f(sb[j]);
        if (mv[j] == 0) v = -1e9f;
        x[j] = v;
        m = fmaxf(m, v);
    }
    #pragma unroll
    for (int off = 1; off < 64; off <<= 1) m = fmaxf(m, __shfl_xor(m, off, 64));

    float lsum = 0.f;
    #pragma unroll
    for (int j = 0; j < 16; ++j) { x[j] = exp2f((x[j] - m) * LOG2E); lsum += x[j]; }
    #pragma unroll
    for (int off = 1; off < 64; off <<= 1) lsum += __shfl_xor(lsum, off, 64);
    const float il = 1.0f / fmaxf(lsum, 1e-30f);

    #pragma unroll
    for (int j = 0; j < 16; ++j) sa[j] = (unsigned short)f2bfs(x[j] * il);
    *(uint4*)&r1[k0]     = *(const uint4*)&sa[0];
    *(uint4*)&r1[k0 + 8] = *(const uint4*)&sa[8];
}

// ---------------------------------------------------------------------------
// values_1: out[b][q][d] = W[b] @ vpT[b]  (MFMA, writes out)
// grid (64 qblk, 8 b), block 256; wave = d-tile.
// ---------------------------------------------------------------------------
__global__ __launch_bounds__(256, 2) void v1_kernel(
    const short* __restrict__ ws_s, const short* __restrict__ w,
    float* __restrict__ out)
{
    const short* vpT = ws_s + VPT_OFF;
    const int t = threadIdx.x, wv = t >> 6, l = t & 63, lr = l & 15, lg = l >> 4;
    const int b = blockIdx.y;
    const int q0 = blockIdx.x * 16;

    f32x4 acc[4];
    #pragma unroll
    for (int j = 0; j < 4; ++j) acc[j] = (f32x4){0.f, 0.f, 0.f, 0.f};

    const short* arow = &w[((size_t)b * NS + q0 + lr) * NS + lg * 8];
    const short* brow = &vpT[((size_t)b * ND + wv * 16 + lr) * NS + lg * 8];
    #pragma unroll 8
    for (int ch = 0; ch < 32; ++ch) {
        bf8_t a  = *(const bf8_t*)(arow + ch * 32);
        bf8_t bb = *(const bf8_t*)(brow + ch * 32);
        acc[ch & 3] = __builtin_amdgcn_mfma_f32_16x16x32_bf16(a, bb, acc[ch & 3], 0, 0, 0);
    }
    f32x4 s;
    #pragma unroll
    for (int r = 0; r < 4; ++r) s[r] = acc[0][r] + acc[1][r] + acc[2][r] + acc[3][r];

    #pragma unroll
    for (int r = 0; r < 4; ++r)
        out[((size_t)b * NS + q0 + lg * 4 + r) * ND + wv * 16 + lr] = s[r];
}

// ---------------------------------------------------------------------------
// values_2: out[b][q][d] += sum_k W[b][q][k] * vbias[q][k][d]  (VALU stream)
// grid 512 (2 q-rows each), block 256; wave owns 256 k's.
// ---------------------------------------------------------------------------
__global__ __launch_bounds__(256, 2) void outv2_kernel(
    const short* __restrict__ w,
    const float* __restrict__ vbias,
    float* __restrict__ out)
{
    __shared__ short Wl[16][1024];          // [b*2+q][k], 32 KB
    __shared__ float otile[4][2][8][64];    // 16 KB

    const int t = threadIdx.x, wv = t >> 6, l = t & 63;
    const int q0 = blockIdx.x * 2;

    {   // stage W slice
        const int rr = t >> 4;              // 0..15 = b*2+q
        const int c0 = (t & 15) * 64;
        const short* src = &w[((size_t)(rr >> 1) * NS + q0 + (rr & 1)) * NS + c0];
        #pragma unroll
        for (int j = 0; j < 8; ++j)
            *(uint4*)&Wl[rr][c0 + j * 8] = *(const uint4*)&src[j * 8];
    }
    __syncthreads();

    const int kq = l >> 4;     // 0..3
    const int dq = l & 15;     // 0..15
    const int kw = wv * 256;

    #pragma unroll
    for (int q = 0; q < 2; ++q) {
        float4 av[8];
        #pragma unroll
        for (int b = 0; b < 8; ++b) av[b] = make_float4(0.f, 0.f, 0.f, 0.f);
        const float* vbq = vbias + (size_t)(q0 + q) * NS * ND;

        #pragma unroll 2
        for (int i = 0; i < 64; ++i) {
            const int k = kw + kq + 4 * i;
            const float4 vb = *(const float4*)&vbq[(size_t)k * ND + 4 * dq];
            #pragma unroll
            for (int b = 0; b < 8; ++b) {
                const float wgt = bf2f((unsigned short)Wl[b * 2 + q][k]);
                av[b].x += wgt * vb.x; av[b].y += wgt * vb.y;
                av[b].z += wgt * vb.z; av[b].w += wgt * vb.w;
            }
        }
        #pragma unroll
        for (int b = 0; b < 8; ++b) {
            #pragma unroll
            for (int off = 16; off <= 32; off <<= 1) {
                av[b].x += __shfl_xor(av[b].x, off, 64);
                av[b].y += __shfl_xor(av[b].y, off, 64);
                av[b].z += __shfl_xor(av[b].z, off, 64);
                av[b].w += __shfl_xor(av[b].w, off, 64);
            }
        }
        if (l < 16) {
            #pragma unroll
            for (int b = 0; b < 8; ++b)
                *(float4*)&otile[wv][q][b][4 * l] = av[b];
        }
    }
    __syncthreads();

    {   // combine 4 waves + v1 partial -> out
        const int q = t >> 7, b = (t >> 4) & 7, dd = (t & 15) * 4;
        float4 s0 = *(const float4*)&otile[0][q][b][dd];
        float4 s1v = *(const float4*)&otile[1][q][b][dd];
        float4 s2v = *(const float4*)&otile[2][q][b][dd];
        float4 s3v = *(const float4*)&otile[3][q][b][dd];
        float* op = &out[((size_t)b * NS + q0 + q) * ND + dd];
        float4 pv = *(const float4*)op;
        float4 o;
        o.x = pv.x + s0.x + s1v.x + s2v.x + s3v.x;
        o.y = pv.y + s0.y + s1v.y + s2v.y + s3v.y;
        o.z = pv.z + s0.z + s1v.z + s2v.z + s3v.z;
        o.w = pv.w + s0.w + s1v.w + s2v.w + s3v.w;
        *(float4*)op = o;
    }
}

extern "C" void kernel_launch(void* const* d_in, const int* in_sizes, int n_in,
                              void* d_out, int out_size, void* d_ws, size_t ws_size,
                              hipStream_t stream) {
    (void)in_sizes; (void)n_in; (void)out_size; (void)ws_size;
    const float* query = (const float*)d_in[0];
    const float* key   = (const float*)d_in[1];
    const float* value = (const float*)d_in[2];
    const float* Wq    = (const float*)d_in[3];
    const float* bq    = (const float*)d_in[4];
    const float* Wk    = (const float*)d_in[5];
    const float* bk    = (const float*)d_in[6];
    const float* Wv    = (const float*)d_in[7];
    const float* bv    = (const float*)d_in[8];
    const float* kbias = (const float*)d_in[9];
    const float* vbias = (const float*)d_in[10];
    const int*   mask  = (const int*)d_in[11];
    short* ws_s = (short*)d_ws;
    short* s1 = ws_s + S1_OFF;
    short* s2 = ws_s + S2_OFF;
    float* outp = (float*)d_out;

    proj_kernel<<<dim3(128, 3), 256, 0, stream>>>(query, key, value, Wq, bq, Wk, bk, Wv, bv, ws_s);
    scores_kernel<<<dim3(8, 64), 256, 0, stream>>>(ws_s, kbias, s1, s2);
    softmax_kernel<<<2048, 256, 0, stream>>>(s1, s2, mask);
    v1_kernel<<<dim3(64, 8), 256, 0, stream>>>(ws_s, s1, outp);
    outv2_kernel<<<512, 256, 0, stream>>>(s1, vbias, outp);
}

// Round 5
// 207.198 us; speedup vs baseline: 2.5026x; 1.1166x over previous
//
#include <hip/hip_runtime.h>
#include <hip/hip_bf16.h>
#include <cstdint>
#include <cstddef>

#define NB 8
#define NS 1024
#define NH 1024
#define ND 64

typedef __attribute__((ext_vector_type(8))) short bf8_t;
typedef __attribute__((ext_vector_type(4))) float f32x4;
typedef __attribute__((ext_vector_type(4))) short short4v;

__device__ __forceinline__ short f2bfs(float x) {
    union { __hip_bfloat16 h; short s; } u;
    u.h = __float2bfloat16(x);
    return u.s;
}
__device__ __forceinline__ float bf2f(unsigned short h) {
    return __uint_as_float(((unsigned int)h) << 16);
}
__device__ __forceinline__ bf8_t pack_bf8(float4 a, float4 b) {
    bf8_t r;
    r[0] = f2bfs(a.x); r[1] = f2bfs(a.y); r[2] = f2bfs(a.z); r[3] = f2bfs(a.w);
    r[4] = f2bfs(b.x); r[5] = f2bfs(b.y); r[6] = f2bfs(b.z); r[7] = f2bfs(b.w);
    return r;
}

// ws layout (shorts):
//   qp [8][1024][64] bf16 (scaled 1/8)   @ QP_OFF
//   kp [8][1024][64] bf16                @ KP_OFF
//   vpT[8][64][1024] bf16                @ VPT_OFF
//   S1 [8][1024][1024] bf16 (scores -> softmax weights, in place) @ S1_OFF
//   S2 [1024][8][1024] bf16 (bias-term scores)                    @ S2_OFF
#define QP_OFF  0
#define KP_OFF  524288
#define VPT_OFF 1048576
#define S1_OFF  1572864
#define S2_OFF  9961472

// ---------------------------------------------------------------------------
// Projection via MFMA: qp (x1/8), kp row-major bf16; vpT [b][d][s] bf16.
// grid (128, 3), block 256 (4 waves x 16 rows = 64 rows/WG).
// ---------------------------------------------------------------------------
__global__ __launch_bounds__(256, 2) void proj_kernel(
    const float* __restrict__ qin, const float* __restrict__ kin, const float* __restrict__ vin,
    const float* __restrict__ Wq, const float* __restrict__ bq,
    const float* __restrict__ Wk, const float* __restrict__ bk,
    const float* __restrict__ Wv, const float* __restrict__ bv,
    short* __restrict__ ws_s)
{
    __shared__ short Wt[64][136];

    const int p = blockIdx.y;
    const float* A    = (p == 0) ? qin : (p == 1) ? kin : vin;
    const float* W    = (p == 0) ? Wq  : (p == 1) ? Wk  : Wv;
    const float* bias = (p == 0) ? bq  : (p == 1) ? bk  : bv;

    const int t  = threadIdx.x;
    const int wv = t >> 6, l = t & 63, lr = l & 15, lg = l >> 4;
    const int rw = blockIdx.x * 64 + wv * 16;

    const int sk  = t & 127;
    const int snh = (t >> 7) * 32;

    f32x4 acc[4];
    #pragma unroll
    for (int n = 0; n < 4; ++n) acc[n] = (f32x4){0.f, 0.f, 0.f, 0.f};

    for (int ch = 0; ch < 8; ++ch) {
        __syncthreads();
        {
            const float* wp = &W[(size_t)(ch * 128 + sk) * ND + snh];
            #pragma unroll
            for (int j = 0; j < 8; ++j) {
                float4 w4 = *(const float4*)&wp[4 * j];
                Wt[snh + 4 * j + 0][sk] = f2bfs(w4.x);
                Wt[snh + 4 * j + 1][sk] = f2bfs(w4.y);
                Wt[snh + 4 * j + 2][sk] = f2bfs(w4.z);
                Wt[snh + 4 * j + 3][sk] = f2bfs(w4.w);
            }
        }
        __syncthreads();
        #pragma unroll
        for (int s = 0; s < 4; ++s) {
            const float* ap = &A[(size_t)(rw + lr) * NH + ch * 128 + s * 32 + lg * 8];
            bf8_t af = pack_bf8(*(const float4*)ap, *(const float4*)(ap + 4));
            #pragma unroll
            for (int n = 0; n < 4; ++n) {
                bf8_t bf = *(const bf8_t*)&Wt[n * 16 + lr][s * 32 + lg * 8];
                acc[n] = __builtin_amdgcn_mfma_f32_16x16x32_bf16(af, bf, acc[n], 0, 0, 0);
            }
        }
    }

    if (p < 2) {
        short* dst = ws_s + ((p == 0) ? QP_OFF : KP_OFF);
        const float sc = (p == 0) ? 0.125f : 1.0f;
        #pragma unroll
        for (int n = 0; n < 4; ++n) {
            const float bs = bias[n * 16 + lr];
            #pragma unroll
            for (int r = 0; r < 4; ++r)
                dst[(size_t)(rw + lg * 4 + r) * ND + n * 16 + lr] = f2bfs((acc[n][r] + bs) * sc);
        }
    } else {
        short* vpT = ws_s + VPT_OFF;
        const int b = rw >> 10;
        const int sbase = (rw & 1023) + lg * 4;
        #pragma unroll
        for (int n = 0; n < 4; ++n) {
            const float bs = bias[n * 16 + lr];
            short4v pk;
            #pragma unroll
            for (int r = 0; r < 4; ++r) pk[r] = f2bfs(acc[n][r] + bs);
            *(short4v*)&vpT[((size_t)b * 64 + n * 16 + lr) * NS + sbase] = pk;
        }
    }
}

// ---------------------------------------------------------------------------
// Scores: S1[b][q][k] = qp_b . kp_b   (content, full-M MFMA)
//         S2[q][b][k] = qp_:  . kbias (bias term, M=8/16, coalesced kbias)
// grid (16 kblk, 64 qblk), block 256; wave owns 16 k's. 4 WG/CU.
// ---------------------------------------------------------------------------
__global__ __launch_bounds__(256, 4) void scores_kernel(
    const short* __restrict__ ws_s,
    const float* __restrict__ kbias,
    short* __restrict__ s1, short* __restrict__ s2)
{
    const short* qp = ws_s + QP_OFF;
    const short* kp = ws_s + KP_OFF;
    const int t = threadIdx.x;
    const int wv = t >> 6, l = t & 63, lr = l & 15, lg = l >> 4;
    const int q0 = blockIdx.y * 16;
    const int k0 = blockIdx.x * 64 + wv * 16;

    // content term
    #pragma unroll
    for (int b = 0; b < 8; ++b) {
        const short* ap = &qp[((size_t)b * NS + q0 + lr) * ND + lg * 8];
        const short* bp = &kp[((size_t)b * NS + k0 + lr) * ND + lg * 8];
        bf8_t a0 = *(const bf8_t*)ap;
        bf8_t a1 = *(const bf8_t*)(ap + 32);
        bf8_t b0 = *(const bf8_t*)bp;
        bf8_t b1 = *(const bf8_t*)(bp + 32);
        f32x4 acc = {0.f, 0.f, 0.f, 0.f};
        acc = __builtin_amdgcn_mfma_f32_16x16x32_bf16(a0, b0, acc, 0, 0, 0);
        acc = __builtin_amdgcn_mfma_f32_16x16x32_bf16(a1, b1, acc, 0, 0, 0);
        #pragma unroll
        for (int r = 0; r < 4; ++r)
            s1[((size_t)b * NS + q0 + lg * 4 + r) * NS + k0 + lr] = f2bfs(acc[r]);
    }

    // bias term: 4 independent (load -> cvt -> mfma) chains in flight
    #pragma unroll 4
    for (int qq = 0; qq < 16; ++qq) {
        const short* ap = &qp[((size_t)(lr & 7) * NS + q0 + qq) * ND + lg * 8];
        bf8_t a0 = *(const bf8_t*)ap;
        bf8_t a1 = *(const bf8_t*)(ap + 32);
        const float* kb = &kbias[((size_t)(q0 + qq) * NS + k0 + lr) * ND + lg * 8];
        bf8_t b0 = pack_bf8(*(const float4*)kb, *(const float4*)(kb + 4));
        bf8_t b1 = pack_bf8(*(const float4*)(kb + 32), *(const float4*)(kb + 36));
        f32x4 acc = {0.f, 0.f, 0.f, 0.f};
        acc = __builtin_amdgcn_mfma_f32_16x16x32_bf16(a0, b0, acc, 0, 0, 0);
        acc = __builtin_amdgcn_mfma_f32_16x16x32_bf16(a1, b1, acc, 0, 0, 0);
        if (lg < 2) {
            #pragma unroll
            for (int r = 0; r < 4; ++r)
                s2[((size_t)(q0 + qq) * NB + lg * 4 + r) * NS + k0 + lr] = f2bfs(acc[r]);
        }
    }
}

// ---------------------------------------------------------------------------
// Softmax: per row (b,q): w = softmax(mask(S1+S2)), written in place to S1.
// grid 2048, block 256; one wave per row.
// ---------------------------------------------------------------------------
__global__ __launch_bounds__(256, 4) void softmax_kernel(
    short* __restrict__ s1, const short* __restrict__ s2,
    const int* __restrict__ mask)
{
    const int t = threadIdx.x, wv = t >> 6, l = t & 63;
    const int row = blockIdx.x * 4 + wv;      // b*NS + q
    const int b = row >> 10, q = row & 1023;
    short* r1 = s1 + (size_t)row * NS;
    const short* r2 = s2 + ((size_t)q * NB + b) * NS;
    const int* mb = mask + b * NS;
    const float LOG2E = 1.4426950408889634f;
    const int k0 = l * 16;

    unsigned short sa[16], sb[16];
    *(uint4*)&sa[0] = *(const uint4*)&r1[k0];
    *(uint4*)&sa[8] = *(const uint4*)&r1[k0 + 8];
    *(uint4*)&sb[0] = *(const uint4*)&r2[k0];
    *(uint4*)&sb[8] = *(const uint4*)&r2[k0 + 8];
    int mv[16];
    #pragma unroll
    for (int j = 0; j < 4; ++j) *(int4*)&mv[4 * j] = *(const int4*)&mb[k0 + 4 * j];

    float x[16];
    float m = -3.0e38f;
    #pragma unroll
    for (int j = 0; j < 16; ++j) {
        float v = bf2f(sa[j]) + bf2f(sb[j]);
        if (mv[j] == 0) v = -1e9f;
        x[j] = v;
        m = fmaxf(m, v);
    }
    #pragma unroll
    for (int off = 1; off < 64; off <<= 1) m = fmaxf(m, __shfl_xor(m, off, 64));

    float lsum = 0.f;
    #pragma unroll
    for (int j = 0; j < 16; ++j) { x[j] = exp2f((x[j] - m) * LOG2E); lsum += x[j]; }
    #pragma unroll
    for (int off = 1; off < 64; off <<= 1) lsum += __shfl_xor(lsum, off, 64);
    const float il = 1.0f / fmaxf(lsum, 1e-30f);

    #pragma unroll
    for (int j = 0; j < 16; ++j) sa[j] = (unsigned short)f2bfs(x[j] * il);
    *(uint4*)&r1[k0]     = *(const uint4*)&sa[0];
    *(uint4*)&r1[k0 + 8] = *(const uint4*)&sa[8];
}

// ---------------------------------------------------------------------------
// values_1: out[b][q][d] = W[b] @ vpT[b]  (MFMA, writes out)
// grid (64 qblk, 8 b), block 256; wave = d-tile.
// ---------------------------------------------------------------------------
__global__ __launch_bounds__(256, 2) void v1_kernel(
    const short* __restrict__ ws_s, const short* __restrict__ w,
    float* __restrict__ out)
{
    const short* vpT = ws_s + VPT_OFF;
    const int t = threadIdx.x, wv = t >> 6, l = t & 63, lr = l & 15, lg = l >> 4;
    const int b = blockIdx.y;
    const int q0 = blockIdx.x * 16;

    f32x4 acc[4];
    #pragma unroll
    for (int j = 0; j < 4; ++j) acc[j] = (f32x4){0.f, 0.f, 0.f, 0.f};

    const short* arow = &w[((size_t)b * NS + q0 + lr) * NS + lg * 8];
    const short* brow = &vpT[((size_t)b * ND + wv * 16 + lr) * NS + lg * 8];
    #pragma unroll 8
    for (int ch = 0; ch < 32; ++ch) {
        bf8_t a  = *(const bf8_t*)(arow + ch * 32);
        bf8_t bb = *(const bf8_t*)(brow + ch * 32);
        acc[ch & 3] = __builtin_amdgcn_mfma_f32_16x16x32_bf16(a, bb, acc[ch & 3], 0, 0, 0);
    }
    f32x4 s;
    #pragma unroll
    for (int r = 0; r < 4; ++r) s[r] = acc[0][r] + acc[1][r] + acc[2][r] + acc[3][r];

    #pragma unroll
    for (int r = 0; r < 4; ++r)
        out[((size_t)b * NS + q0 + lg * 4 + r) * ND + wv * 16 + lr] = s[r];
}

// ---------------------------------------------------------------------------
// values_2: out[b][q][d] += sum_k W[b][q][k] * vbias[q][k][d]  (VALU stream)
// grid 1024 (1 q-row each), block 256; wave owns 256 k's. 4 WG/CU.
// ---------------------------------------------------------------------------
__global__ __launch_bounds__(256, 4) void outv2_kernel(
    const short* __restrict__ w,
    const float* __restrict__ vbias,
    float* __restrict__ out)
{
    __shared__ short Wl[8][1024];           // [b][k], 16 KB
    __shared__ float otile[4][8][64];       // 8 KB

    const int t = threadIdx.x, wv = t >> 6, l = t & 63;
    const int q = blockIdx.x;

    {   // stage W slice: 8 rows x 1024 shorts
        const int rr = t >> 5;              // 0..7 = b
        const int c0 = (t & 31) * 32;
        const short* src = &w[((size_t)rr * NS + q) * NS + c0];
        #pragma unroll
        for (int j = 0; j < 4; ++j)
            *(uint4*)&Wl[rr][c0 + j * 8] = *(const uint4*)&src[j * 8];
    }
    __syncthreads();

    const int kq = l >> 4;     // 0..3
    const int dq = l & 15;     // 0..15
    const int kw = wv * 256;
    const float* vbq = vbias + (size_t)q * NS * ND;

    float4 av[8];
    #pragma unroll
    for (int b = 0; b < 8; ++b) av[b] = make_float4(0.f, 0.f, 0.f, 0.f);

    #pragma unroll 4
    for (int i = 0; i < 64; ++i) {
        const int k = kw + kq + 4 * i;
        const float4 vb = *(const float4*)&vbq[(size_t)k * ND + 4 * dq];
        #pragma unroll
        for (int b = 0; b < 8; ++b) {
            const float wgt = bf2f((unsigned short)Wl[b][k]);
            av[b].x += wgt * vb.x; av[b].y += wgt * vb.y;
            av[b].z += wgt * vb.z; av[b].w += wgt * vb.w;
        }
    }
    #pragma unroll
    for (int b = 0; b < 8; ++b) {
        #pragma unroll
        for (int off = 16; off <= 32; off <<= 1) {
            av[b].x += __shfl_xor(av[b].x, off, 64);
            av[b].y += __shfl_xor(av[b].y, off, 64);
            av[b].z += __shfl_xor(av[b].z, off, 64);
            av[b].w += __shfl_xor(av[b].w, off, 64);
        }
    }
    if (l < 16) {
        #pragma unroll
        for (int b = 0; b < 8; ++b)
            *(float4*)&otile[wv][b][4 * l] = av[b];
    }
    __syncthreads();

    if (t < 128) {   // combine 4 waves + v1 partial -> out
        const int b = t >> 4, dd = (t & 15) * 4;
        float4 s0 = *(const float4*)&otile[0][b][dd];
        float4 s1v = *(const float4*)&otile[1][b][dd];
        float4 s2v = *(const float4*)&otile[2][b][dd];
        float4 s3v = *(const float4*)&otile[3][b][dd];
        float* op = &out[((size_t)b * NS + q) * ND + dd];
        float4 pv = *(const float4*)op;
        float4 o;
        o.x = pv.x + s0.x + s1v.x + s2v.x + s3v.x;
        o.y = pv.y + s0.y + s1v.y + s2v.y + s3v.y;
        o.z = pv.z + s0.z + s1v.z + s2v.z + s3v.z;
        o.w = pv.w + s0.w + s1v.w + s2v.w + s3v.w;
        *(float4*)op = o;
    }
}

extern "C" void kernel_launch(void* const* d_in, const int* in_sizes, int n_in,
                              void* d_out, int out_size, void* d_ws, size_t ws_size,
                              hipStream_t stream) {
    (void)in_sizes; (void)n_in; (void)out_size; (void)ws_size;
    const float* query = (const float*)d_in[0];
    const float* key   = (const float*)d_in[1];
    const float* value = (const float*)d_in[2];
    const float* Wq    = (const float*)d_in[3];
    const float* bq    = (const float*)d_in[4];
    const float* Wk    = (const float*)d_in[5];
    const float* bk    = (const float*)d_in[6];
    const float* Wv    = (const float*)d_in[7];
    const float* bv    = (const float*)d_in[8];
    const float* kbias = (const float*)d_in[9];
    const float* vbias = (const float*)d_in[10];
    const int*   mask  = (const int*)d_in[11];
    short* ws_s = (short*)d_ws;
    short* s1 = ws_s + S1_OFF;
    short* s2 = ws_s + S2_OFF;
    float* outp = (float*)d_out;

    proj_kernel<<<dim3(128, 3), 256, 0, stream>>>(query, key, value, Wq, bq, Wk, bk, Wv, bv, ws_s);
    scores_kernel<<<dim3(16, 64), 256, 0, stream>>>(ws_s, kbias, s1, s2);
    softmax_kernel<<<2048, 256, 0, stream>>>(s1, s2, mask);
    v1_kernel<<<dim3(64, 8), 256, 0, stream>>>(ws_s, s1, outp);
    outv2_kernel<<<1024, 256, 0, stream>>>(s1, vbias, outp);
}

// Round 6
// 191.083 us; speedup vs baseline: 2.7136x; 1.0843x over previous
//
#include <hip/hip_runtime.h>
#include <hip/hip_bf16.h>
#include <cstdint>
#include <cstddef>

#define NB 8
#define NS 1024
#define NH 1024
#define ND 64

typedef __attribute__((ext_vector_type(8))) short bf8_t;
typedef __attribute__((ext_vector_type(4))) float f32x4;
typedef __attribute__((ext_vector_type(4))) short short4v;

__device__ __forceinline__ short f2bfs(float x) {
    union { __hip_bfloat16 h; short s; } u;
    u.h = __float2bfloat16(x);
    return u.s;
}
__device__ __forceinline__ float bf2f(unsigned short h) {
    return __uint_as_float(((unsigned int)h) << 16);
}
__device__ __forceinline__ bf8_t pack_bf8(float4 a, float4 b) {
    bf8_t r;
    r[0] = f2bfs(a.x); r[1] = f2bfs(a.y); r[2] = f2bfs(a.z); r[3] = f2bfs(a.w);
    r[4] = f2bfs(b.x); r[5] = f2bfs(b.y); r[6] = f2bfs(b.z); r[7] = f2bfs(b.w);
    return r;
}

// ws layout (shorts):
//   qp [8][1024][64] bf16 (scaled 1/8)   @ QP_OFF
//   kp [8][1024][64] bf16                @ KP_OFF
//   vpT[8][64][1024] bf16                @ VPT_OFF
//   S1 [8][1024][1024] bf16 (content scores -> weights, in place) @ S1_OFF
#define QP_OFF  0
#define KP_OFF  524288
#define VPT_OFF 1048576
#define S1_OFF  1572864

// ---------------------------------------------------------------------------
// Projection via MFMA, double-buffered W staging.
// grid (128, 3), block 256 (4 waves x 16 rows = 64 rows/WG).
// ---------------------------------------------------------------------------
__global__ __launch_bounds__(256, 2) void proj_kernel(
    const float* __restrict__ qin, const float* __restrict__ kin, const float* __restrict__ vin,
    const float* __restrict__ Wq, const float* __restrict__ bq,
    const float* __restrict__ Wk, const float* __restrict__ bk,
    const float* __restrict__ Wv, const float* __restrict__ bv,
    short* __restrict__ ws_s)
{
    __shared__ short Wt[2][64][136];

    const int p = blockIdx.y;
    const float* A    = (p == 0) ? qin : (p == 1) ? kin : vin;
    const float* W    = (p == 0) ? Wq  : (p == 1) ? Wk  : Wv;
    const float* bias = (p == 0) ? bq  : (p == 1) ? bk  : bv;

    const int t  = threadIdx.x;
    const int wv = t >> 6, l = t & 63, lr = l & 15, lg = l >> 4;
    const int rw = blockIdx.x * 64 + wv * 16;

    const int sk  = t & 127;
    const int snh = (t >> 7) * 32;

    f32x4 acc[4];
    #pragma unroll
    for (int n = 0; n < 4; ++n) acc[n] = (f32x4){0.f, 0.f, 0.f, 0.f};

    // stage chunk 0 into buf 0
    {
        const float* wp = &W[(size_t)sk * ND + snh];
        #pragma unroll
        for (int j = 0; j < 8; ++j) {
            float4 w4 = *(const float4*)&wp[4 * j];
            Wt[0][snh + 4 * j + 0][sk] = f2bfs(w4.x);
            Wt[0][snh + 4 * j + 1][sk] = f2bfs(w4.y);
            Wt[0][snh + 4 * j + 2][sk] = f2bfs(w4.z);
            Wt[0][snh + 4 * j + 3][sk] = f2bfs(w4.w);
        }
    }
    __syncthreads();

    for (int ch = 0; ch < 8; ++ch) {
        const int cur = ch & 1;
        if (ch < 7) {   // stage next chunk into the other buffer
            const float* wp = &W[(size_t)((ch + 1) * 128 + sk) * ND + snh];
            #pragma unroll
            for (int j = 0; j < 8; ++j) {
                float4 w4 = *(const float4*)&wp[4 * j];
                Wt[cur ^ 1][snh + 4 * j + 0][sk] = f2bfs(w4.x);
                Wt[cur ^ 1][snh + 4 * j + 1][sk] = f2bfs(w4.y);
                Wt[cur ^ 1][snh + 4 * j + 2][sk] = f2bfs(w4.z);
                Wt[cur ^ 1][snh + 4 * j + 3][sk] = f2bfs(w4.w);
            }
        }
        #pragma unroll
        for (int s = 0; s < 4; ++s) {
            const float* ap = &A[(size_t)(rw + lr) * NH + ch * 128 + s * 32 + lg * 8];
            bf8_t af = pack_bf8(*(const float4*)ap, *(const float4*)(ap + 4));
            #pragma unroll
            for (int n = 0; n < 4; ++n) {
                bf8_t bf = *(const bf8_t*)&Wt[cur][n * 16 + lr][s * 32 + lg * 8];
                acc[n] = __builtin_amdgcn_mfma_f32_16x16x32_bf16(af, bf, acc[n], 0, 0, 0);
            }
        }
        __syncthreads();
    }

    if (p < 2) {
        short* dst = ws_s + ((p == 0) ? QP_OFF : KP_OFF);
        const float sc = (p == 0) ? 0.125f : 1.0f;
        #pragma unroll
        for (int n = 0; n < 4; ++n) {
            const float bs = bias[n * 16 + lr];
            #pragma unroll
            for (int r = 0; r < 4; ++r)
                dst[(size_t)(rw + lg * 4 + r) * ND + n * 16 + lr] = f2bfs((acc[n][r] + bs) * sc);
        }
    } else {
        short* vpT = ws_s + VPT_OFF;
        const int b = rw >> 10;
        const int sbase = (rw & 1023) + lg * 4;
        #pragma unroll
        for (int n = 0; n < 4; ++n) {
            const float bs = bias[n * 16 + lr];
            short4v pk;
            #pragma unroll
            for (int r = 0; r < 4; ++r) pk[r] = f2bfs(acc[n][r] + bs);
            *(short4v*)&vpT[((size_t)b * 64 + n * 16 + lr) * NS + sbase] = pk;
        }
    }
}

// ---------------------------------------------------------------------------
// Content scores only: S1[b][q][k] = qp_b . kp_b
// grid (16 kblk, 64 qblk), block 256; wave owns 16 k's.
// ---------------------------------------------------------------------------
__global__ __launch_bounds__(256, 4) void scores_c_kernel(
    const short* __restrict__ ws_s, short* __restrict__ s1)
{
    const short* qp = ws_s + QP_OFF;
    const short* kp = ws_s + KP_OFF;
    const int t = threadIdx.x;
    const int wv = t >> 6, l = t & 63, lr = l & 15, lg = l >> 4;
    const int q0 = blockIdx.y * 16;
    const int k0 = blockIdx.x * 64 + wv * 16;

    #pragma unroll
    for (int b = 0; b < 8; ++b) {
        const short* ap = &qp[((size_t)b * NS + q0 + lr) * ND + lg * 8];
        const short* bp = &kp[((size_t)b * NS + k0 + lr) * ND + lg * 8];
        bf8_t a0 = *(const bf8_t*)ap;
        bf8_t a1 = *(const bf8_t*)(ap + 32);
        bf8_t b0 = *(const bf8_t*)bp;
        bf8_t b1 = *(const bf8_t*)(bp + 32);
        f32x4 acc = {0.f, 0.f, 0.f, 0.f};
        acc = __builtin_amdgcn_mfma_f32_16x16x32_bf16(a0, b0, acc, 0, 0, 0);
        acc = __builtin_amdgcn_mfma_f32_16x16x32_bf16(a1, b1, acc, 0, 0, 0);
        #pragma unroll
        for (int r = 0; r < 4; ++r)
            s1[((size_t)b * NS + q0 + lg * 4 + r) * NS + k0 + lr] = f2bfs(acc[r]);
    }
}

// ---------------------------------------------------------------------------
// Mega kernel: per q row -- kbias stream (bias scores, MFMA) -> softmax ->
// vbias stream (out). Writes normalized weights back to s1 for v1.
// grid 1024, block 256, 4 WG/CU.
// ---------------------------------------------------------------------------
__global__ __launch_bounds__(256, 4) void mega_kernel(
    const short* __restrict__ ws_s,
    short* __restrict__ s1,
    const float* __restrict__ kbias,
    const float* __restrict__ vbias,
    const int* __restrict__ mask,
    float* __restrict__ out)
{
    __shared__ short Wt[8][1024];     // normalized weights [b][k], survives to phase C
    __shared__ short Sb[8][1032];     // bias scores [b][k]; reused as otile in phase C

    const short* qp = ws_s + QP_OFF;
    const int q = blockIdx.x, t = threadIdx.x;
    const int wv = t >> 6, l = t & 63, lr = l & 15, lg = l >> 4;

    // ---- phase A: bias scores S2[b][k] = q_b . kbias[q,k] via MFMA ----
    {
        const bf8_t aq0 = *(const bf8_t*)&qp[((size_t)(lr & 7) * NS + q) * ND + lg * 8];
        const bf8_t aq1 = *(const bf8_t*)&qp[((size_t)(lr & 7) * NS + q) * ND + 32 + lg * 8];
        const float* kbq = kbias + (size_t)q * NS * ND;

        #pragma unroll 4
        for (int it = 0; it < 16; ++it) {
            const int k0 = wv * 256 + it * 16;
            const float* kb = &kbq[(size_t)(k0 + lr) * ND + lg * 8];
            bf8_t b0 = pack_bf8(*(const float4*)kb, *(const float4*)(kb + 4));
            bf8_t b1 = pack_bf8(*(const float4*)(kb + 32), *(const float4*)(kb + 36));
            f32x4 acc = {0.f, 0.f, 0.f, 0.f};
            acc = __builtin_amdgcn_mfma_f32_16x16x32_bf16(aq0, b0, acc, 0, 0, 0);
            acc = __builtin_amdgcn_mfma_f32_16x16x32_bf16(aq1, b1, acc, 0, 0, 0);
            if (lg < 2) {
                #pragma unroll
                for (int r = 0; r < 4; ++r)
                    Sb[lg * 4 + r][k0 + lr] = f2bfs(acc[r]);
            }
        }
    }
    __syncthreads();

    // ---- phase B: softmax over k for each b; weights -> Wt LDS + s1 global ----
    {
        const int b = t >> 5, idx = t & 31;
        const int kk = idx * 32;
        short* r1 = s1 + ((size_t)b * NS + q) * NS + kk;
        const int* mb = mask + b * NS + kk;
        const float LOG2E = 1.4426950408889634f;

        float x[32];
        float m = -3.0e38f;
        #pragma unroll
        for (int c = 0; c < 4; ++c) {
            uint4 a4 = *(const uint4*)&r1[8 * c];
            uint4 b4 = *(const uint4*)&Sb[b][kk + 8 * c];
            int4 m0 = *(const int4*)&mb[8 * c];
            int4 m1 = *(const int4*)&mb[8 * c + 4];
            const unsigned short* ap = (const unsigned short*)&a4;
            const unsigned short* bp = (const unsigned short*)&b4;
            const int* mp = (const int*)&m0;
            const int* mq = (const int*)&m1;
            #pragma unroll
            for (int j = 0; j < 8; ++j) {
                float v = bf2f(ap[j]) + bf2f(bp[j]);
                const int mvv = (j < 4) ? mp[j] : mq[j - 4];
                v = (mvv == 0) ? -1e9f : v;
                x[8 * c + j] = v;
                m = fmaxf(m, v);
            }
        }
        #pragma unroll
        for (int off = 1; off < 32; off <<= 1) m = fmaxf(m, __shfl_xor(m, off, 32));

        float lsum = 0.f;
        #pragma unroll
        for (int j = 0; j < 32; ++j) { x[j] = exp2f((x[j] - m) * LOG2E); lsum += x[j]; }
        #pragma unroll
        for (int off = 1; off < 32; off <<= 1) lsum += __shfl_xor(lsum, off, 32);
        const float il = 1.0f / fmaxf(lsum, 1e-30f);

        unsigned short wv16[32];
        #pragma unroll
        for (int j = 0; j < 32; ++j) wv16[j] = (unsigned short)f2bfs(x[j] * il);
        #pragma unroll
        for (int c = 0; c < 4; ++c) {
            *(uint4*)&Wt[b][kk + 8 * c] = *(const uint4*)&wv16[8 * c];
            *(uint4*)&r1[8 * c]         = *(const uint4*)&wv16[8 * c];
        }
    }
    __syncthreads();

    // ---- phase C: out[b][q][:] = sum_k w[b,k] * vbias[q,k,:] ----
    float* otile = (float*)&Sb[0][0];   // [4][8][64] f32 = 8 KB, aliases Sb
    {
        const int kq = l >> 4, dq = l & 15;
        const int kw = wv * 256;
        const float* vbq = vbias + (size_t)q * NS * ND;

        float4 av[8];
        #pragma unroll
        for (int b = 0; b < 8; ++b) av[b] = make_float4(0.f, 0.f, 0.f, 0.f);

        #pragma unroll 4
        for (int i = 0; i < 64; ++i) {
            const int k = kw + kq + 4 * i;
            const float4 vb = *(const float4*)&vbq[(size_t)k * ND + 4 * dq];
            #pragma unroll
            for (int b = 0; b < 8; ++b) {
                const float wgt = bf2f((unsigned short)Wt[b][k]);
                av[b].x += wgt * vb.x; av[b].y += wgt * vb.y;
                av[b].z += wgt * vb.z; av[b].w += wgt * vb.w;
            }
        }
        #pragma unroll
        for (int b = 0; b < 8; ++b) {
            #pragma unroll
            for (int off = 16; off <= 32; off <<= 1) {
                av[b].x += __shfl_xor(av[b].x, off, 64);
                av[b].y += __shfl_xor(av[b].y, off, 64);
                av[b].z += __shfl_xor(av[b].z, off, 64);
                av[b].w += __shfl_xor(av[b].w, off, 64);
            }
        }
        if (l < 16) {
            #pragma unroll
            for (int b = 0; b < 8; ++b)
                *(float4*)&otile[((size_t)wv * 8 + b) * 64 + 4 * l] = av[b];
        }
    }
    __syncthreads();

    if (t < 128) {
        const int b = t >> 4, dd = (t & 15) * 4;
        float4 s = make_float4(0.f, 0.f, 0.f, 0.f);
        #pragma unroll
        for (int w4 = 0; w4 < 4; ++w4) {
            float4 r = *(const float4*)&otile[((size_t)w4 * 8 + b) * 64 + dd];
            s.x += r.x; s.y += r.y; s.z += r.z; s.w += r.w;
        }
        *(float4*)&out[((size_t)b * NS + q) * ND + dd] = s;
    }
}

// ---------------------------------------------------------------------------
// values_1: out[b][q][d] += W[b] @ vpT[b]  (MFMA, RMW -- runs after mega)
// grid (64 qblk, 8 b), block 256; wave = d-tile.
// ---------------------------------------------------------------------------
__global__ __launch_bounds__(256, 2) void v1_kernel(
    const short* __restrict__ ws_s, const short* __restrict__ w,
    float* __restrict__ out)
{
    const short* vpT = ws_s + VPT_OFF;
    const int t = threadIdx.x, wv = t >> 6, l = t & 63, lr = l & 15, lg = l >> 4;
    const int b = blockIdx.y;
    const int q0 = blockIdx.x * 16;

    f32x4 acc[4];
    #pragma unroll
    for (int j = 0; j < 4; ++j) acc[j] = (f32x4){0.f, 0.f, 0.f, 0.f};

    const short* arow = &w[((size_t)b * NS + q0 + lr) * NS + lg * 8];
    const short* brow = &vpT[((size_t)b * ND + wv * 16 + lr) * NS + lg * 8];
    #pragma unroll 8
    for (int ch = 0; ch < 32; ++ch) {
        bf8_t a  = *(const bf8_t*)(arow + ch * 32);
        bf8_t bb = *(const bf8_t*)(brow + ch * 32);
        acc[ch & 3] = __builtin_amdgcn_mfma_f32_16x16x32_bf16(a, bb, acc[ch & 3], 0, 0, 0);
    }
    f32x4 s;
    #pragma unroll
    for (int r = 0; r < 4; ++r) s[r] = acc[0][r] + acc[1][r] + acc[2][r] + acc[3][r];

    #pragma unroll
    for (int r = 0; r < 4; ++r) {
        float* op = &out[((size_t)b * NS + q0 + lg * 4 + r) * ND + wv * 16 + lr];
        *op = *op + s[r];
    }
}

extern "C" void kernel_launch(void* const* d_in, const int* in_sizes, int n_in,
                              void* d_out, int out_size, void* d_ws, size_t ws_size,
                              hipStream_t stream) {
    (void)in_sizes; (void)n_in; (void)out_size; (void)ws_size;
    const float* query = (const float*)d_in[0];
    const float* key   = (const float*)d_in[1];
    const float* value = (const float*)d_in[2];
    const float* Wq    = (const float*)d_in[3];
    const float* bq    = (const float*)d_in[4];
    const float* Wk    = (const float*)d_in[5];
    const float* bk    = (const float*)d_in[6];
    const float* Wv    = (const float*)d_in[7];
    const float* bv    = (const float*)d_in[8];
    const float* kbias = (const float*)d_in[9];
    const float* vbias = (const float*)d_in[10];
    const int*   mask  = (const int*)d_in[11];
    short* ws_s = (short*)d_ws;
    short* s1 = ws_s + S1_OFF;
    float* outp = (float*)d_out;

    proj_kernel<<<dim3(128, 3), 256, 0, stream>>>(query, key, value, Wq, bq, Wk, bk, Wv, bv, ws_s);
    scores_c_kernel<<<dim3(16, 64), 256, 0, stream>>>(ws_s, s1);
    mega_kernel<<<1024, 256, 0, stream>>>(ws_s, s1, kbias, vbias, mask, outp);
    v1_kernel<<<dim3(64, 8), 256, 0, stream>>>(ws_s, s1, outp);
}